// Round 8
// baseline (832.263 us; speedup 1.0000x reference)
//
#include <hip/hip_runtime.h>
#include <hip/hip_fp16.h>
#include <math.h>

// Problem constants: NE=1e6, NR=1000, D=32, B=2^20, CURV=1
#define NR_ 1000
#define NE_ 1000000
#define D_ 32
#define HALF_ 16
#define EMB_DIM 33            // fp32 entity row: [x0, spatial(32)]
#define H16_BYTES ((size_t)NE_ * 64)   // fp16 entity table: 64 B rows
#define T16_HALVES 64                  // fp16 tab row: 64 halves = 128 B
#define T16_BYTES ((size_t)NR_ * T16_HALVES * 2)     // 128 KB
#define HP_BYTES ((size_t)NR_ * 16)                  // 16 KB float4 table

#define GRID_BLOCKS 2048               // 8 blocks/CU x 256 CUs -> ALL resident
#define REPACK_THREADS (NE_ * 4)       // 4,000,000 repack units (4 lanes/row)
#define TAB_THREADS (NR_ * 4)          // 4,000 tab units

// Persistent-grid barrier counter (module-scope; reset by trailing kernel so
// hip-graph replays start from 0).
__device__ unsigned int g_arrive = 0;

// ---------------------------------------------------------------------------
// FUSED kernel: phase A (entity repack fp32->fp16 interleaved + relation
// table build) -> device-scope grid barrier -> phase B (scoring).
// Residency guarantee for the spin barrier: __launch_bounds__(256, 8) caps
// VGPR at 64 (8 waves/EU), zero LDS -> 8 blocks/CU x 256 CU = 2048 = grid.
// Barrier: release (threadfence + agent-release add: L2 writeback of all
// phase-A h16/tab stores) then acquire spin (agent-acquire load: invalidates
// stale poison lines the harness fill may have left in other XCDs' L2/L1).
// Timeout (~0.8 s) turns any residency bug into a wrong answer, not a hang.
// Phase layouts identical to R7 (proven, absmax 2.44e-4):
//   h16 row r, chunk q (16 B): {sp[4q..4q+3], sp[16+4q..+3]} fp16
//   tab16 row r: line0 chunk q {cos[4q..], sin[4q..]}, line1 {kt_a, kt_b}
//   hp_tab[r] = {cosh(rap0), sinh(rap0), cosh(vn), 0}
// ---------------------------------------------------------------------------
__global__ __launch_bounds__(256, 8) void fused_kernel(
    const int* __restrict__ heads, const int* __restrict__ rels,
    const int* __restrict__ tails, const float* __restrict__ emb,
    const float* __restrict__ boost_w, const float* __restrict__ rot_w,
    const float* __restrict__ trans_w, const float* __restrict__ bias,
    unsigned int* __restrict__ h16, unsigned short* __restrict__ tab16,
    float4* __restrict__ hp_tab, float* __restrict__ out, int n) {
  const int tid = threadIdx.x;
  const long base0 = (long)blockIdx.x * 256 + tid;
  const long gstride = (long)GRID_BLOCKS * 256;   // 524,288

  union U2 { unsigned int u; __half2 h; };

  // ---------------- Phase A: repack + relation tables ----------------
  for (long t = base0; t < (long)REPACK_THREADS + TAB_THREADS; t += gstride) {
    if (t < REPACK_THREADS) {
      const int r = (int)(t >> 2), q = (int)(t & 3);
      // Scalar cached reads of a contiguous region: every 64 B line is
      // fetched once and fully used via L1/L2 (R3-proven, = LDS version).
      const float* p = emb + (size_t)r * EMB_DIM + 1 + 4 * q;
      float a0 = p[0], a1 = p[1], a2 = p[2], a3 = p[3];
      float b0 = p[HALF_], b1 = p[HALF_ + 1], b2 = p[HALF_ + 2], b3 = p[HALF_ + 3];
      U2 c0, c1, c2, c3;
      c0.h = __half2(__float2half_rn(a0), __float2half_rn(a1));
      c1.h = __half2(__float2half_rn(a2), __float2half_rn(a3));
      c2.h = __half2(__float2half_rn(b0), __float2half_rn(b1));
      c3.h = __half2(__float2half_rn(b2), __float2half_rn(b3));
      *reinterpret_cast<uint4*>(h16 + (size_t)r * 16 + 4 * q) =
          make_uint4(c0.u, c1.u, c2.u, c3.u);
    } else {
      const int t2 = (int)(t - REPACK_THREADS);
      const int r = t2 >> 2, q = t2 & 3;   // 4-lane groups stay wave-aligned
      const float* ro = rot_w   + (size_t)r * D_ + 4 * q;
      const float* ta = trans_w + (size_t)r * D_ + 4 * q;
      const float* tb = ta + HALF_;
      float ta0 = ta[0], ta1 = ta[1], ta2 = ta[2], ta3 = ta[3];
      float tb0 = tb[0], tb1 = tb[1], tb2 = tb[2], tb3 = tb[3];
      float s2 = ta0 * ta0;
      s2 = fmaf(ta1, ta1, s2); s2 = fmaf(ta2, ta2, s2); s2 = fmaf(ta3, ta3, s2);
      s2 = fmaf(tb0, tb0, s2); s2 = fmaf(tb1, tb1, s2);
      s2 = fmaf(tb2, tb2, s2); s2 = fmaf(tb3, tb3, s2);
      s2 += __shfl_xor(s2, 1);
      s2 += __shfl_xor(s2, 2);
      float vn = sqrtf(fmaxf(0.01f * s2, 1e-6f));
      float k  = sinhf(vn) / vn * 0.1f;
      const float cc0 = cosf(ro[0]), cc1 = cosf(ro[1]),
                  cc2 = cosf(ro[2]), cc3 = cosf(ro[3]);
      const float ss0 = sinf(ro[0]), ss1 = sinf(ro[1]),
                  ss2 = sinf(ro[2]), ss3 = sinf(ro[3]);
      U2 p0, p1, p2, p3;
      p0.h = __half2(__float2half_rn(cc0), __float2half_rn(cc1));
      p1.h = __half2(__float2half_rn(cc2), __float2half_rn(cc3));
      p2.h = __half2(__float2half_rn(ss0), __float2half_rn(ss1));
      p3.h = __half2(__float2half_rn(ss2), __float2half_rn(ss3));
      *reinterpret_cast<uint4*>(tab16 + (size_t)r * T16_HALVES + 8 * q) =
          make_uint4(p0.u, p1.u, p2.u, p3.u);
      p0.h = __half2(__float2half_rn(k * ta0), __float2half_rn(k * ta1));
      p1.h = __half2(__float2half_rn(k * ta2), __float2half_rn(k * ta3));
      p2.h = __half2(__float2half_rn(k * tb0), __float2half_rn(k * tb1));
      p3.h = __half2(__float2half_rn(k * tb2), __float2half_rn(k * tb3));
      *reinterpret_cast<uint4*>(tab16 + (size_t)r * T16_HALVES + 32 + 8 * q) =
          make_uint4(p0.u, p1.u, p2.u, p3.u);
      if (q == 0) {
        float rap = fminf(fmaxf(boost_w[(size_t)r * D_], -2.f), 2.f);
        hp_tab[r] = make_float4(coshf(rap), sinhf(rap), coshf(vn), 0.f);
      }
    }
  }

  // ---------------- Grid barrier (all 2048 blocks resident) ----------------
  __syncthreads();                       // drains this block's stores (vmcnt 0)
  if (tid == 0) {
    __threadfence();                     // device-scope release of phase A
    __hip_atomic_fetch_add(&g_arrive, 1u, __ATOMIC_RELEASE,
                           __HIP_MEMORY_SCOPE_AGENT);
    const long long tstart = (long long)clock64();
    while (__hip_atomic_load(&g_arrive, __ATOMIC_ACQUIRE,
                             __HIP_MEMORY_SCOPE_AGENT) < GRID_BLOCKS) {
      __builtin_amdgcn_s_sleep(16);
      if ((long long)clock64() - tstart > 2000000000LL) break;  // ~0.8 s guard
    }
  }
  __syncthreads();
  __threadfence();                       // reader-side ordering for the block

  // ---------------- Phase B: scoring (R7-proven arithmetic) ----------------
  const long limit = (long)4 * n;        // 4 lanes per element
  for (long gt = base0; gt < limit; gt += gstride) {
    const int q = (int)(gt & 3);         // == tid & 3 (stride mult. of 4)
    const int e = (int)(gt >> 2);

    const int hd = heads[e];
    const int rl = rels[e];
    const int tl = tails[e];

    const uint4 hv = *reinterpret_cast<const uint4*>(h16 + (size_t)hd * 16 + 4 * q);
    const uint4 tv = *reinterpret_cast<const uint4*>(h16 + (size_t)tl * 16 + 4 * q);
    const uint4 rv = *reinterpret_cast<const uint4*>(
        tab16 + (size_t)rl * T16_HALVES + 8 * q);
    const uint4 kv = *reinterpret_cast<const uint4*>(
        tab16 + (size_t)rl * T16_HALVES + 32 + 8 * q);
    const float4 hp = hp_tab[rl];
    const float bsum = bias[hd] + bias[tl];

    U2 rc0, rc1, rs0, rs1;
    rc0.u = rv.x; rc1.u = rv.y; rs0.u = rv.z; rs1.u = rv.w;
    const float2 c01 = __half22float2(rc0.h), c23 = __half22float2(rc1.h);
    const float2 s01 = __half22float2(rs0.h), s23 = __half22float2(rs1.h);
    U2 k0, k1, k2, k3;
    k0.u = kv.x; k1.u = kv.y; k2.u = kv.z; k3.u = kv.w;
    const float2 ka01 = __half22float2(k0.h), ka23 = __half22float2(k1.h);
    const float2 kb01 = __half22float2(k2.h), kb23 = __half22float2(k3.h);

    U2 u0, u1, u2, u3;
    u0.u = hv.x; u1.u = hv.y; u2.u = hv.z; u3.u = hv.w;
    const float2 fa01 = __half22float2(u0.h);
    const float2 fa23 = __half22float2(u1.h);
    const float2 fb01 = __half22float2(u2.h);
    const float2 fb23 = __half22float2(u3.h);
    const float a0 = fa01.x, a1 = fa01.y, a2 = fa23.x, a3 = fa23.y;
    const float b0 = fb01.x, b1 = fb01.y, b2 = fb23.x, b3 = fb23.y;

    float hsq = a0 * a0;
    hsq = fmaf(a1, a1, hsq); hsq = fmaf(a2, a2, hsq); hsq = fmaf(a3, a3, hsq);
    hsq = fmaf(b0, b0, hsq); hsq = fmaf(b1, b1, hsq);
    hsq = fmaf(b2, b2, hsq); hsq = fmaf(b3, b3, hsq);
    hsq += __shfl_xor(hsq, 1);
    hsq += __shfl_xor(hsq, 2);
    const float x0 = sqrtf(1.f + hsq);

    float rA0 = c01.x * a0 - s01.x * b0;
    float rA1 = c01.y * a1 - s01.y * b1;
    float rA2 = c23.x * a2 - s23.x * b2;
    float rA3 = c23.y * a3 - s23.y * b3;
    const float rB0 = fmaf(s01.x, a0, c01.x * b0);
    const float rB1 = fmaf(s01.y, a1, c01.y * b1);
    const float rB2 = fmaf(s23.x, a2, c23.x * b2);
    const float rB3 = fmaf(s23.y, a3, c23.y * b3);

    if (q == 0) rA0 = fmaf(x0, hp.y, rA0 * hp.x);
    const float cvn = hp.z;

    const float sA0 = fmaf(cvn, rA0, ka01.x);
    const float sA1 = fmaf(cvn, rA1, ka01.y);
    const float sA2 = fmaf(cvn, rA2, ka23.x);
    const float sA3 = fmaf(cvn, rA3, ka23.y);
    const float sB0 = fmaf(cvn, rB0, kb01.x);
    const float sB1 = fmaf(cvn, rB1, kb01.y);
    const float sB2 = fmaf(cvn, rB2, kb23.x);
    const float sB3 = fmaf(cvn, rB3, kb23.y);

    float n2 = sA0 * sA0;
    n2 = fmaf(sA1, sA1, n2); n2 = fmaf(sA2, sA2, n2); n2 = fmaf(sA3, sA3, n2);
    n2 = fmaf(sB0, sB0, n2); n2 = fmaf(sB1, sB1, n2);
    n2 = fmaf(sB2, sB2, n2); n2 = fmaf(sB3, sB3, n2);
    n2 += __shfl_xor(n2, 1);
    n2 += __shfl_xor(n2, 2);
    const float ht0 = sqrtf(1.f + n2);

    U2 w0, w1, w2, w3;
    w0.u = tv.x; w1.u = tv.y; w2.u = tv.z; w3.u = tv.w;
    const float2 ta01 = __half22float2(w0.h);
    const float2 ta23 = __half22float2(w1.h);
    const float2 tb01 = __half22float2(w2.h);
    const float2 tb23 = __half22float2(w3.h);

    float dot = sA0 * ta01.x;
    dot = fmaf(sA1, ta01.y, dot); dot = fmaf(sA2, ta23.x, dot);
    dot = fmaf(sA3, ta23.y, dot);
    dot = fmaf(sB0, tb01.x, dot); dot = fmaf(sB1, tb01.y, dot);
    dot = fmaf(sB2, tb23.x, dot); dot = fmaf(sB3, tb23.y, dot);

    float tsq = ta01.x * ta01.x;
    tsq = fmaf(ta01.y, ta01.y, tsq); tsq = fmaf(ta23.x, ta23.x, tsq);
    tsq = fmaf(ta23.y, ta23.y, tsq);
    tsq = fmaf(tb01.x, tb01.x, tsq); tsq = fmaf(tb01.y, tb01.y, tsq);
    tsq = fmaf(tb23.x, tb23.x, tsq); tsq = fmaf(tb23.y, tb23.y, tsq);

    dot += __shfl_xor(dot, 1);
    dot += __shfl_xor(dot, 2);
    tsq += __shfl_xor(tsq, 1);
    tsq += __shfl_xor(tsq, 2);
    const float t0 = sqrtf(1.f + tsq);

    const float neg_inner = fmaf(ht0, t0, -dot);
    const float ic = fmaxf(neg_inner, 1.0f + 1e-6f);
    const float dist = acoshf(ic);
    if (q == 0) out[e] = bsum - dist * dist;
  }
}

// Trailing reset so the next graph replay starts with g_arrive == 0.
__global__ void reset_kernel() {
  if (threadIdx.x == 0 && blockIdx.x == 0)
    __hip_atomic_store(&g_arrive, 0u, __ATOMIC_RELAXED,
                       __HIP_MEMORY_SCOPE_AGENT);
}

// ---------------------------------------------------------------------------
// Fallback (ws too small): fully inline fp32 scalar path (proven).
// ---------------------------------------------------------------------------
__global__ __launch_bounds__(256) void lorentz_fallback_kernel(
    const int* __restrict__ heads, const int* __restrict__ rels,
    const int* __restrict__ tails, const float* __restrict__ emb,
    const float* __restrict__ boost_w, const float* __restrict__ rot_w,
    const float* __restrict__ trans_w, const float* __restrict__ bias,
    float* __restrict__ out, int n) {
  int i = blockIdx.x * blockDim.x + threadIdx.x;
  if (i >= n) return;
  int hd = heads[i], rl = rels[i], tl = tails[i];
  const float* hrow = emb + (size_t)hd * EMB_DIM;
  const float* trow = emb + (size_t)tl * EMB_DIM;
  const float* ro = rot_w   + (size_t)rl * D_;
  const float* tr = trans_w + (size_t)rl * D_;
  float c[HALF_], s[HALF_], kt[D_];
  #pragma unroll
  for (int j = 0; j < HALF_; ++j) { float th = ro[j]; c[j] = cosf(th); s[j] = sinf(th); }
  float s2 = 0.f;
  #pragma unroll
  for (int j = 0; j < D_; ++j) { float v = tr[j]; s2 = fmaf(v, v, s2); }
  float vn = sqrtf(fmaxf(0.01f * s2, 1e-6f));
  float cvn = coshf(vn);
  float k = sinhf(vn) / vn * 0.1f;
  #pragma unroll
  for (int j = 0; j < D_; ++j) kt[j] = k * tr[j];
  float rap = fminf(fmaxf(boost_w[(size_t)rl * D_], -2.f), 2.f);
  float c0 = coshf(rap), s0 = sinhf(rap);
  float x0 = hrow[0];
  float r[D_];
  #pragma unroll
  for (int j = 0; j < HALF_; ++j) {
    float a = hrow[1 + j], b = hrow[1 + HALF_ + j];
    r[j] = c[j] * a - s[j] * b;
    r[HALF_ + j] = s[j] * a + c[j] * b;
  }
  r[0] = fmaf(x0, s0, r[0] * c0);
  float t0 = trow[0], n2 = 0.f, dot = 0.f;
  #pragma unroll
  for (int j = 0; j < D_; ++j) {
    float rsv = fmaf(cvn, r[j], kt[j]);
    n2  = fmaf(rsv, rsv, n2);
    dot = fmaf(rsv, trow[1 + j], dot);
  }
  float ht0 = sqrtf(1.f + n2);
  float neg_inner = fmaf(ht0, t0, -dot);
  float ic = fmaxf(neg_inner, 1.0f + 1e-6f);
  float dist = acoshf(ic);
  out[i] = bias[hd] + bias[tl] - dist * dist;
}

extern "C" void kernel_launch(void* const* d_in, const int* in_sizes, int n_in,
                              void* d_out, int out_size, void* d_ws, size_t ws_size,
                              hipStream_t stream) {
  const int*   heads  = (const int*)d_in[0];
  const int*   rels   = (const int*)d_in[1];
  const int*   tails  = (const int*)d_in[2];
  const float* emb    = (const float*)d_in[3];
  const float* boostw = (const float*)d_in[4];
  const float* rotw   = (const float*)d_in[5];
  const float* transw = (const float*)d_in[6];
  const float* bias   = (const float*)d_in[7];
  float* out = (float*)d_out;
  int n = in_sizes[0];  // B = 1048576

  dim3 block(256);

  if (ws_size >= H16_BYTES + T16_BYTES + HP_BYTES) {
    unsigned int* h16 = (unsigned int*)d_ws;
    unsigned short* tab16 = (unsigned short*)((char*)d_ws + H16_BYTES);
    float4* hp_tab = (float4*)((char*)d_ws + H16_BYTES + T16_BYTES);
    fused_kernel<<<dim3(GRID_BLOCKS), block, 0, stream>>>(
        heads, rels, tails, emb, boostw, rotw, transw, bias,
        h16, tab16, hp_tab, out, n);
    reset_kernel<<<dim3(1), dim3(64), 0, stream>>>();
  } else {
    dim3 grid((n + 255) / 256);
    lorentz_fallback_kernel<<<grid, block, 0, stream>>>(
        heads, rels, tails, emb, boostw, rotw, transw, bias, out, n);
  }
}

// Round 10
// 286.503 us; speedup vs baseline: 2.9049x; 2.9049x over previous
//
#include <hip/hip_runtime.h>
#include <hip/hip_fp16.h>
#include <math.h>

// Problem constants: NE=1e6, NR=1000, D=32, B=2^20, CURV=1
#define NR_ 1000
#define NE_ 1000000
#define D_ 32
#define HALF_ 16
#define EMB_DIM 33            // fp32 entity row: [x0, spatial(32)]
#define H16_BYTES ((size_t)NE_ * 64)   // fp16 entity table: 64 B rows
#define T16_HALVES 64                  // fp16 tab row: 64 halves = 128 B
#define T16_BYTES ((size_t)NR_ * T16_HALVES * 2)     // 128 KB
#define HP_BYTES ((size_t)NR_ * 16)                  // 16 KB float4 table
#define REPACK_BLOCKS 15625            // 15625*256 = 4,000,000 = NE*4 lanes
#define TAB_BLOCKS 16                  // 16*256 = 4096 >= NR*4 lanes

// Native clang vector type: __builtin_nontemporal_store rejects HIP's
// uint4 class type (R9 compile error) but accepts ext_vector_type.
typedef unsigned int uintv4 __attribute__((ext_vector_type(4)));

// ---------------------------------------------------------------------------
// Kernel 0 (fused prep) — R7-proven structure + NON-TEMPORAL h16 stores.
// prep streams 132 MB of reads AND 64 MB of writes through L2 concurrently;
// nt stores skip the dirty-line writeback churn (main re-reads h16 from L3
// regardless — R2 proved main's duration is cache-tier-invariant).
// Entity rows: fp16 INTERLEAVED, chunk q = {sp[4q..4q+3], sp[16+4q..+3]}.
// Relation row r (128 B stride): line0 chunk q {cos[4q..], sin[4q..]},
// line1 chunk q {kt_a[4q..], kt_b[16+4q..]}.
// hp_tab[r] = {cosh(rap0), sinh(rap0), cosh(vn), 0} (16 KB, L1-resident).
// ---------------------------------------------------------------------------
__global__ __launch_bounds__(256) void prep_kernel(
    const float* __restrict__ emb, const float* __restrict__ boost_w,
    const float* __restrict__ rot_w, const float* __restrict__ trans_w,
    unsigned int* __restrict__ h16, unsigned short* __restrict__ tab16,
    float4* __restrict__ hp_tab) {
  const int b = blockIdx.x;
  union U2 { unsigned int u; __half2 h; };
  if (b < REPACK_BLOCKS) {
    const int t = b * 256 + threadIdx.x;              // < 4,000,000
    const int r = t >> 2, q = t & 3;
    // Plain cached reads: contiguous region, every 64 B line fetched once
    // and fully consumed via L1/L2 line-sharing (nt-loads proven harmful, R1).
    const float* p = emb + (size_t)r * EMB_DIM + 1 + 4 * q;
    float a0 = p[0], a1 = p[1], a2 = p[2], a3 = p[3];
    float b0 = p[HALF_], b1 = p[HALF_ + 1], b2 = p[HALF_ + 2], b3 = p[HALF_ + 3];
    U2 c0, c1, c2, c3;
    c0.h = __half2(__float2half_rn(a0), __float2half_rn(a1));
    c1.h = __half2(__float2half_rn(a2), __float2half_rn(a3));
    c2.h = __half2(__float2half_rn(b0), __float2half_rn(b1));
    c3.h = __half2(__float2half_rn(b2), __float2half_rn(b3));
    uintv4 v = {c0.u, c1.u, c2.u, c3.u};
    uintv4* dst = reinterpret_cast<uintv4*>(h16 + (size_t)r * 16 + 4 * q);
    __builtin_nontemporal_store(v, dst);              // 16B nt store
    return;
  }
  // ---- tab build: 4 lanes per relation ----
  const int t = (b - REPACK_BLOCKS) * 256 + threadIdx.x;
  const int r = t >> 2, q = t & 3;
  if (r >= NR_) return;
  const float* ro = rot_w   + (size_t)r * D_ + 4 * q;
  const float* ta = trans_w + (size_t)r * D_ + 4 * q;
  const float* tb = ta + HALF_;

  float ta0 = ta[0], ta1 = ta[1], ta2 = ta[2], ta3 = ta[3];
  float tb0 = tb[0], tb1 = tb[1], tb2 = tb[2], tb3 = tb[3];
  float s2 = ta0 * ta0;
  s2 = fmaf(ta1, ta1, s2); s2 = fmaf(ta2, ta2, s2); s2 = fmaf(ta3, ta3, s2);
  s2 = fmaf(tb0, tb0, s2); s2 = fmaf(tb1, tb1, s2);
  s2 = fmaf(tb2, tb2, s2); s2 = fmaf(tb3, tb3, s2);
  s2 += __shfl_xor(s2, 1);
  s2 += __shfl_xor(s2, 2);

  float vn = sqrtf(fmaxf(0.01f * s2, 1e-6f));
  float k  = sinhf(vn) / vn * 0.1f;

  const float cc0 = cosf(ro[0]), cc1 = cosf(ro[1]),
              cc2 = cosf(ro[2]), cc3 = cosf(ro[3]);
  const float ss0 = sinf(ro[0]), ss1 = sinf(ro[1]),
              ss2 = sinf(ro[2]), ss3 = sinf(ro[3]);

  U2 p0, p1, p2, p3;
  p0.h = __half2(__float2half_rn(cc0), __float2half_rn(cc1));
  p1.h = __half2(__float2half_rn(cc2), __float2half_rn(cc3));
  p2.h = __half2(__float2half_rn(ss0), __float2half_rn(ss1));
  p3.h = __half2(__float2half_rn(ss2), __float2half_rn(ss3));
  *reinterpret_cast<uint4*>(tab16 + (size_t)r * T16_HALVES + 8 * q) =
      make_uint4(p0.u, p1.u, p2.u, p3.u);
  p0.h = __half2(__float2half_rn(k * ta0), __float2half_rn(k * ta1));
  p1.h = __half2(__float2half_rn(k * ta2), __float2half_rn(k * ta3));
  p2.h = __half2(__float2half_rn(k * tb0), __float2half_rn(k * tb1));
  p3.h = __half2(__float2half_rn(k * tb2), __float2half_rn(k * tb3));
  *reinterpret_cast<uint4*>(tab16 + (size_t)r * T16_HALVES + 32 + 8 * q) =
      make_uint4(p0.u, p1.u, p2.u, p3.u);

  if (q == 0) {
    float rap = fminf(fmaxf(boost_w[(size_t)r * D_], -2.f), 2.f);
    hp_tab[r] = make_float4(coshf(rap), sinhf(rap), coshf(vn), 0.f);
  }
}

// ---------------------------------------------------------------------------
// Kernel 1: main scoring (R7-proven, best measured config: 272.0 us total).
// 4-lane-cooperative, LDS-free, fp16 everywhere. Per-element divergent line
// requests ~6.4: head 1 + tail 1 + rot 1 + kt 1 + bias 2 + hp ~0 (L1).
// Latency-bound regime (R2: duration invariant to cache tier; R6/R8:
// concurrency increases null) — this is at its measured MLP floor.
// ---------------------------------------------------------------------------
__global__ __launch_bounds__(256) void lorentz_coop_kernel(
    const int* __restrict__ heads, const int* __restrict__ rels,
    const int* __restrict__ tails, const unsigned int* __restrict__ h16,
    const unsigned short* __restrict__ tab16, const float4* __restrict__ hp_tab,
    const float* __restrict__ bias, float* __restrict__ out, int n) {
  const int q = threadIdx.x & 3;                      // dim-chunk within group
  const int e = (blockIdx.x * 256 + threadIdx.x) >> 2; // element id
  const int i = (e < n) ? e : (n - 1);                // clamp: lanes stay active

  const int hd = heads[i];
  const int rl = rels[i];
  const int tl = tails[i];

  // ---- Issue ALL divergent loads back-to-back (deep vmcnt queue) ----
  const uint4 hv = *reinterpret_cast<const uint4*>(h16 + (size_t)hd * 16 + 4 * q);
  const uint4 tv = *reinterpret_cast<const uint4*>(h16 + (size_t)tl * 16 + 4 * q);
  const uint4 rv = *reinterpret_cast<const uint4*>(
      tab16 + (size_t)rl * T16_HALVES + 8 * q);          // {c0..3, s0..3}
  const uint4 kv = *reinterpret_cast<const uint4*>(
      tab16 + (size_t)rl * T16_HALVES + 32 + 8 * q);     // {kta0..3, ktb0..3}
  const float4 hp = hp_tab[rl];   // L1-resident (16 KB), broadcast in group
  const float bsum = bias[hd] + bias[tl];

  union U2 { unsigned int u; __half2 h; };
  U2 rc0, rc1, rs0, rs1;
  rc0.u = rv.x; rc1.u = rv.y; rs0.u = rv.z; rs1.u = rv.w;
  const float2 c01 = __half22float2(rc0.h), c23 = __half22float2(rc1.h);
  const float2 s01 = __half22float2(rs0.h), s23 = __half22float2(rs1.h);
  U2 k0, k1, k2, k3;
  k0.u = kv.x; k1.u = kv.y; k2.u = kv.z; k3.u = kv.w;
  const float2 ka01 = __half22float2(k0.h), ka23 = __half22float2(k1.h);
  const float2 kb01 = __half22float2(k2.h), kb23 = __half22float2(k3.h);

  U2 u0, u1, u2, u3;
  u0.u = hv.x; u1.u = hv.y; u2.u = hv.z; u3.u = hv.w;
  const float2 fa01 = __half22float2(u0.h);
  const float2 fa23 = __half22float2(u1.h);
  const float2 fb01 = __half22float2(u2.h);
  const float2 fb23 = __half22float2(u3.h);
  const float a0 = fa01.x, a1 = fa01.y, a2 = fa23.x, a3 = fa23.y;
  const float b0 = fb01.x, b1 = fb01.y, b2 = fb23.x, b3 = fb23.y;

  float hsq = a0 * a0;
  hsq = fmaf(a1, a1, hsq); hsq = fmaf(a2, a2, hsq); hsq = fmaf(a3, a3, hsq);
  hsq = fmaf(b0, b0, hsq); hsq = fmaf(b1, b1, hsq);
  hsq = fmaf(b2, b2, hsq); hsq = fmaf(b3, b3, hsq);
  hsq += __shfl_xor(hsq, 1);
  hsq += __shfl_xor(hsq, 2);
  const float x0 = sqrtf(1.f + hsq);          // head time component

  float rA0 = c01.x * a0 - s01.x * b0;
  float rA1 = c01.y * a1 - s01.y * b1;
  float rA2 = c23.x * a2 - s23.x * b2;
  float rA3 = c23.y * a3 - s23.y * b3;
  const float rB0 = fmaf(s01.x, a0, c01.x * b0);
  const float rB1 = fmaf(s01.y, a1, c01.y * b1);
  const float rB2 = fmaf(s23.x, a2, c23.x * b2);
  const float rB3 = fmaf(s23.y, a3, c23.y * b3);

  if (q == 0) rA0 = fmaf(x0, hp.y, rA0 * hp.x);   // boost: spatial dim 0 only
  const float cvn = hp.z;

  const float sA0 = fmaf(cvn, rA0, ka01.x);
  const float sA1 = fmaf(cvn, rA1, ka01.y);
  const float sA2 = fmaf(cvn, rA2, ka23.x);
  const float sA3 = fmaf(cvn, rA3, ka23.y);
  const float sB0 = fmaf(cvn, rB0, kb01.x);
  const float sB1 = fmaf(cvn, rB1, kb01.y);
  const float sB2 = fmaf(cvn, rB2, kb23.x);
  const float sB3 = fmaf(cvn, rB3, kb23.y);

  float n2 = sA0 * sA0;
  n2 = fmaf(sA1, sA1, n2); n2 = fmaf(sA2, sA2, n2); n2 = fmaf(sA3, sA3, n2);
  n2 = fmaf(sB0, sB0, n2); n2 = fmaf(sB1, sB1, n2);
  n2 = fmaf(sB2, sB2, n2); n2 = fmaf(sB3, sB3, n2);
  n2 += __shfl_xor(n2, 1);
  n2 += __shfl_xor(n2, 2);
  const float ht0 = sqrtf(1.f + n2);

  U2 w0, w1, w2, w3;
  w0.u = tv.x; w1.u = tv.y; w2.u = tv.z; w3.u = tv.w;
  const float2 ta01 = __half22float2(w0.h);
  const float2 ta23 = __half22float2(w1.h);
  const float2 tb01 = __half22float2(w2.h);
  const float2 tb23 = __half22float2(w3.h);

  float dot = sA0 * ta01.x;
  dot = fmaf(sA1, ta01.y, dot); dot = fmaf(sA2, ta23.x, dot);
  dot = fmaf(sA3, ta23.y, dot);
  dot = fmaf(sB0, tb01.x, dot); dot = fmaf(sB1, tb01.y, dot);
  dot = fmaf(sB2, tb23.x, dot); dot = fmaf(sB3, tb23.y, dot);

  float tsq = ta01.x * ta01.x;
  tsq = fmaf(ta01.y, ta01.y, tsq); tsq = fmaf(ta23.x, ta23.x, tsq);
  tsq = fmaf(ta23.y, ta23.y, tsq);
  tsq = fmaf(tb01.x, tb01.x, tsq); tsq = fmaf(tb01.y, tb01.y, tsq);
  tsq = fmaf(tb23.x, tb23.x, tsq); tsq = fmaf(tb23.y, tb23.y, tsq);

  dot += __shfl_xor(dot, 1);
  dot += __shfl_xor(dot, 2);
  tsq += __shfl_xor(tsq, 1);
  tsq += __shfl_xor(tsq, 2);
  const float t0 = sqrtf(1.f + tsq);          // tail time component

  const float neg_inner = fmaf(ht0, t0, -dot); // -lorentz_inner
  const float ic = fmaxf(neg_inner, 1.0f + 1e-6f);
  const float dist = acoshf(ic);
  if (q == 0 && e < n) out[e] = bsum - dist * dist;
}

// ---------------------------------------------------------------------------
// Fallback (ws too small): fully inline fp32 scalar path (proven).
// ---------------------------------------------------------------------------
__global__ __launch_bounds__(256) void lorentz_fallback_kernel(
    const int* __restrict__ heads, const int* __restrict__ rels,
    const int* __restrict__ tails, const float* __restrict__ emb,
    const float* __restrict__ boost_w, const float* __restrict__ rot_w,
    const float* __restrict__ trans_w, const float* __restrict__ bias,
    float* __restrict__ out, int n) {
  int i = blockIdx.x * blockDim.x + threadIdx.x;
  if (i >= n) return;
  int hd = heads[i], rl = rels[i], tl = tails[i];
  const float* hrow = emb + (size_t)hd * EMB_DIM;
  const float* trow = emb + (size_t)tl * EMB_DIM;
  const float* ro = rot_w   + (size_t)rl * D_;
  const float* tr = trans_w + (size_t)rl * D_;
  float c[HALF_], s[HALF_], kt[D_];
  #pragma unroll
  for (int j = 0; j < HALF_; ++j) { float th = ro[j]; c[j] = cosf(th); s[j] = sinf(th); }
  float s2 = 0.f;
  #pragma unroll
  for (int j = 0; j < D_; ++j) { float v = tr[j]; s2 = fmaf(v, v, s2); }
  float vn = sqrtf(fmaxf(0.01f * s2, 1e-6f));
  float cvn = coshf(vn);
  float k = sinhf(vn) / vn * 0.1f;
  #pragma unroll
  for (int j = 0; j < D_; ++j) kt[j] = k * tr[j];
  float rap = fminf(fmaxf(boost_w[(size_t)rl * D_], -2.f), 2.f);
  float c0 = coshf(rap), s0 = sinhf(rap);
  float x0 = hrow[0];
  float r[D_];
  #pragma unroll
  for (int j = 0; j < HALF_; ++j) {
    float a = hrow[1 + j], b = hrow[1 + HALF_ + j];
    r[j] = c[j] * a - s[j] * b;
    r[HALF_ + j] = s[j] * a + c[j] * b;
  }
  r[0] = fmaf(x0, s0, r[0] * c0);
  float t0 = trow[0], n2 = 0.f, dot = 0.f;
  #pragma unroll
  for (int j = 0; j < D_; ++j) {
    float rsv = fmaf(cvn, r[j], kt[j]);
    n2  = fmaf(rsv, rsv, n2);
    dot = fmaf(rsv, trow[1 + j], dot);
  }
  float ht0 = sqrtf(1.f + n2);
  float neg_inner = fmaf(ht0, t0, -dot);
  float ic = fmaxf(neg_inner, 1.0f + 1e-6f);
  float dist = acoshf(ic);
  out[i] = bias[hd] + bias[tl] - dist * dist;
}

extern "C" void kernel_launch(void* const* d_in, const int* in_sizes, int n_in,
                              void* d_out, int out_size, void* d_ws, size_t ws_size,
                              hipStream_t stream) {
  const int*   heads  = (const int*)d_in[0];
  const int*   rels   = (const int*)d_in[1];
  const int*   tails  = (const int*)d_in[2];
  const float* emb    = (const float*)d_in[3];
  const float* boostw = (const float*)d_in[4];
  const float* rotw   = (const float*)d_in[5];
  const float* transw = (const float*)d_in[6];
  const float* bias   = (const float*)d_in[7];
  float* out = (float*)d_out;
  int n = in_sizes[0];  // B = 1048576

  dim3 block(256);

  if (ws_size >= H16_BYTES + T16_BYTES + HP_BYTES) {
    unsigned int* h16 = (unsigned int*)d_ws;
    unsigned short* tab16 = (unsigned short*)((char*)d_ws + H16_BYTES);
    float4* hp_tab = (float4*)((char*)d_ws + H16_BYTES + T16_BYTES);
    prep_kernel<<<dim3(REPACK_BLOCKS + TAB_BLOCKS), block, 0, stream>>>(
        emb, boostw, rotw, transw, h16, tab16, hp_tab);
    dim3 grid_main((n + 63) / 64);   // 4 lanes per element, 64 elems/block
    lorentz_coop_kernel<<<grid_main, block, 0, stream>>>(
        heads, rels, tails, h16, tab16, hp_tab, bias, out, n);
  } else {
    dim3 grid((n + 255) / 256);
    lorentz_fallback_kernel<<<grid, block, 0, stream>>>(
        heads, rels, tails, emb, boostw, rotw, transw, bias, out, n);
  }
}

// Round 11
// 273.384 us; speedup vs baseline: 3.0443x; 1.0480x over previous
//
#include <hip/hip_runtime.h>
#include <hip/hip_fp16.h>
#include <math.h>

// Problem constants: NE=1e6, NR=1000, D=32, B=2^20, CURV=1
#define NR_ 1000
#define NE_ 1000000
#define D_ 32
#define HALF_ 16
#define EMB_DIM 33            // fp32 entity row: [x0, spatial(32)]
#define H16_BYTES ((size_t)NE_ * 64)   // fp16 entity table: 64 B rows
#define T16_HALVES 64                  // fp16 tab row: 64 halves = 128 B
#define T16_BYTES ((size_t)NR_ * T16_HALVES * 2)     // 128 KB
#define HP_BYTES ((size_t)NR_ * 16)                  // 16 KB float4 table
#define REPACK_BLOCKS 15625            // 15625*256 = 4,000,000 = NE*4 lanes
#define TAB_BLOCKS 16                  // 16*256 = 4096 >= NR*4 lanes

// ---------------------------------------------------------------------------
// Kernel 0 (fused prep) — R7-proven EXACT revert (best measured: 272.0 us).
// PLAIN cached stores: R10 proved nt-stores regress +14.5 us (non-allocating
// -> h16 served from HBM ~900cy instead of L3; main is latency-sensitive at
// its ~6.4 req/elem). Plain stores keep h16 L2/L3-resident for main.
// Entity rows: fp16 INTERLEAVED, chunk q = {sp[4q..4q+3], sp[16+4q..+3]}.
// Relation row r (128 B stride): line0 chunk q {cos[4q..], sin[4q..]},
// line1 chunk q {kt_a[4q..], kt_b[16+4q..]}.
// hp_tab[r] = {cosh(rap0), sinh(rap0), cosh(vn), 0} (16 KB, L1-resident).
// ---------------------------------------------------------------------------
__global__ __launch_bounds__(256) void prep_kernel(
    const float* __restrict__ emb, const float* __restrict__ boost_w,
    const float* __restrict__ rot_w, const float* __restrict__ trans_w,
    unsigned int* __restrict__ h16, unsigned short* __restrict__ tab16,
    float4* __restrict__ hp_tab) {
  const int b = blockIdx.x;
  union U2 { unsigned int u; __half2 h; };
  if (b < REPACK_BLOCKS) {
    const int t = b * 256 + threadIdx.x;              // < 4,000,000
    const int r = t >> 2, q = t & 3;
    // Plain cached reads: contiguous region, every 64 B line fetched once
    // and fully consumed via L1/L2 line-sharing (nt-loads proven harmful, R1).
    const float* p = emb + (size_t)r * EMB_DIM + 1 + 4 * q;
    float a0 = p[0], a1 = p[1], a2 = p[2], a3 = p[3];
    float b0 = p[HALF_], b1 = p[HALF_ + 1], b2 = p[HALF_ + 2], b3 = p[HALF_ + 3];
    U2 c0, c1, c2, c3;
    c0.h = __half2(__float2half_rn(a0), __float2half_rn(a1));
    c1.h = __half2(__float2half_rn(a2), __float2half_rn(a3));
    c2.h = __half2(__float2half_rn(b0), __float2half_rn(b1));
    c3.h = __half2(__float2half_rn(b2), __float2half_rn(b3));
    *reinterpret_cast<uint4*>(h16 + (size_t)r * 16 + 4 * q) =
        make_uint4(c0.u, c1.u, c2.u, c3.u);           // 16B plain store
    return;
  }
  // ---- tab build: 4 lanes per relation ----
  const int t = (b - REPACK_BLOCKS) * 256 + threadIdx.x;
  const int r = t >> 2, q = t & 3;
  if (r >= NR_) return;
  const float* ro = rot_w   + (size_t)r * D_ + 4 * q;
  const float* ta = trans_w + (size_t)r * D_ + 4 * q;
  const float* tb = ta + HALF_;

  float ta0 = ta[0], ta1 = ta[1], ta2 = ta[2], ta3 = ta[3];
  float tb0 = tb[0], tb1 = tb[1], tb2 = tb[2], tb3 = tb[3];
  float s2 = ta0 * ta0;
  s2 = fmaf(ta1, ta1, s2); s2 = fmaf(ta2, ta2, s2); s2 = fmaf(ta3, ta3, s2);
  s2 = fmaf(tb0, tb0, s2); s2 = fmaf(tb1, tb1, s2);
  s2 = fmaf(tb2, tb2, s2); s2 = fmaf(tb3, tb3, s2);
  s2 += __shfl_xor(s2, 1);
  s2 += __shfl_xor(s2, 2);

  float vn = sqrtf(fmaxf(0.01f * s2, 1e-6f));
  float k  = sinhf(vn) / vn * 0.1f;

  const float cc0 = cosf(ro[0]), cc1 = cosf(ro[1]),
              cc2 = cosf(ro[2]), cc3 = cosf(ro[3]);
  const float ss0 = sinf(ro[0]), ss1 = sinf(ro[1]),
              ss2 = sinf(ro[2]), ss3 = sinf(ro[3]);

  U2 p0, p1, p2, p3;
  p0.h = __half2(__float2half_rn(cc0), __float2half_rn(cc1));
  p1.h = __half2(__float2half_rn(cc2), __float2half_rn(cc3));
  p2.h = __half2(__float2half_rn(ss0), __float2half_rn(ss1));
  p3.h = __half2(__float2half_rn(ss2), __float2half_rn(ss3));
  *reinterpret_cast<uint4*>(tab16 + (size_t)r * T16_HALVES + 8 * q) =
      make_uint4(p0.u, p1.u, p2.u, p3.u);
  p0.h = __half2(__float2half_rn(k * ta0), __float2half_rn(k * ta1));
  p1.h = __half2(__float2half_rn(k * ta2), __float2half_rn(k * ta3));
  p2.h = __half2(__float2half_rn(k * tb0), __float2half_rn(k * tb1));
  p3.h = __half2(__float2half_rn(k * tb2), __float2half_rn(k * tb3));
  *reinterpret_cast<uint4*>(tab16 + (size_t)r * T16_HALVES + 32 + 8 * q) =
      make_uint4(p0.u, p1.u, p2.u, p3.u);

  if (q == 0) {
    float rap = fminf(fmaxf(boost_w[(size_t)r * D_], -2.f), 2.f);
    hp_tab[r] = make_float4(coshf(rap), sinhf(rap), coshf(vn), 0.f);
  }
}

// ---------------------------------------------------------------------------
// Kernel 1: main scoring (R7-proven, best measured config: 272.0 us total).
// 4-lane-cooperative, LDS-free, fp16 everywhere. Per-element divergent line
// requests ~6.4: head 1 + tail 1 + rot 1 + kt 1 + bias 2 + hp ~0 (L1).
// Latency x MLP-bound regime (R2: request-issue-serialized at high req/elem;
// R6/R8: concurrency levers null; R10: HBM-tier placement hurts -> L3
// placement of h16 is optimal). This is the measured floor for this op.
// ---------------------------------------------------------------------------
__global__ __launch_bounds__(256) void lorentz_coop_kernel(
    const int* __restrict__ heads, const int* __restrict__ rels,
    const int* __restrict__ tails, const unsigned int* __restrict__ h16,
    const unsigned short* __restrict__ tab16, const float4* __restrict__ hp_tab,
    const float* __restrict__ bias, float* __restrict__ out, int n) {
  const int q = threadIdx.x & 3;                      // dim-chunk within group
  const int e = (blockIdx.x * 256 + threadIdx.x) >> 2; // element id
  const int i = (e < n) ? e : (n - 1);                // clamp: lanes stay active

  const int hd = heads[i];
  const int rl = rels[i];
  const int tl = tails[i];

  // ---- Issue ALL divergent loads back-to-back (deep vmcnt queue) ----
  const uint4 hv = *reinterpret_cast<const uint4*>(h16 + (size_t)hd * 16 + 4 * q);
  const uint4 tv = *reinterpret_cast<const uint4*>(h16 + (size_t)tl * 16 + 4 * q);
  const uint4 rv = *reinterpret_cast<const uint4*>(
      tab16 + (size_t)rl * T16_HALVES + 8 * q);          // {c0..3, s0..3}
  const uint4 kv = *reinterpret_cast<const uint4*>(
      tab16 + (size_t)rl * T16_HALVES + 32 + 8 * q);     // {kta0..3, ktb0..3}
  const float4 hp = hp_tab[rl];   // L1-resident (16 KB), broadcast in group
  const float bsum = bias[hd] + bias[tl];

  union U2 { unsigned int u; __half2 h; };
  U2 rc0, rc1, rs0, rs1;
  rc0.u = rv.x; rc1.u = rv.y; rs0.u = rv.z; rs1.u = rv.w;
  const float2 c01 = __half22float2(rc0.h), c23 = __half22float2(rc1.h);
  const float2 s01 = __half22float2(rs0.h), s23 = __half22float2(rs1.h);
  U2 k0, k1, k2, k3;
  k0.u = kv.x; k1.u = kv.y; k2.u = kv.z; k3.u = kv.w;
  const float2 ka01 = __half22float2(k0.h), ka23 = __half22float2(k1.h);
  const float2 kb01 = __half22float2(k2.h), kb23 = __half22float2(k3.h);

  U2 u0, u1, u2, u3;
  u0.u = hv.x; u1.u = hv.y; u2.u = hv.z; u3.u = hv.w;
  const float2 fa01 = __half22float2(u0.h);
  const float2 fa23 = __half22float2(u1.h);
  const float2 fb01 = __half22float2(u2.h);
  const float2 fb23 = __half22float2(u3.h);
  const float a0 = fa01.x, a1 = fa01.y, a2 = fa23.x, a3 = fa23.y;
  const float b0 = fb01.x, b1 = fb01.y, b2 = fb23.x, b3 = fb23.y;

  float hsq = a0 * a0;
  hsq = fmaf(a1, a1, hsq); hsq = fmaf(a2, a2, hsq); hsq = fmaf(a3, a3, hsq);
  hsq = fmaf(b0, b0, hsq); hsq = fmaf(b1, b1, hsq);
  hsq = fmaf(b2, b2, hsq); hsq = fmaf(b3, b3, hsq);
  hsq += __shfl_xor(hsq, 1);
  hsq += __shfl_xor(hsq, 2);
  const float x0 = sqrtf(1.f + hsq);          // head time component

  float rA0 = c01.x * a0 - s01.x * b0;
  float rA1 = c01.y * a1 - s01.y * b1;
  float rA2 = c23.x * a2 - s23.x * b2;
  float rA3 = c23.y * a3 - s23.y * b3;
  const float rB0 = fmaf(s01.x, a0, c01.x * b0);
  const float rB1 = fmaf(s01.y, a1, c01.y * b1);
  const float rB2 = fmaf(s23.x, a2, c23.x * b2);
  const float rB3 = fmaf(s23.y, a3, c23.y * b3);

  if (q == 0) rA0 = fmaf(x0, hp.y, rA0 * hp.x);   // boost: spatial dim 0 only
  const float cvn = hp.z;

  const float sA0 = fmaf(cvn, rA0, ka01.x);
  const float sA1 = fmaf(cvn, rA1, ka01.y);
  const float sA2 = fmaf(cvn, rA2, ka23.x);
  const float sA3 = fmaf(cvn, rA3, ka23.y);
  const float sB0 = fmaf(cvn, rB0, kb01.x);
  const float sB1 = fmaf(cvn, rB1, kb01.y);
  const float sB2 = fmaf(cvn, rB2, kb23.x);
  const float sB3 = fmaf(cvn, rB3, kb23.y);

  float n2 = sA0 * sA0;
  n2 = fmaf(sA1, sA1, n2); n2 = fmaf(sA2, sA2, n2); n2 = fmaf(sA3, sA3, n2);
  n2 = fmaf(sB0, sB0, n2); n2 = fmaf(sB1, sB1, n2);
  n2 = fmaf(sB2, sB2, n2); n2 = fmaf(sB3, sB3, n2);
  n2 += __shfl_xor(n2, 1);
  n2 += __shfl_xor(n2, 2);
  const float ht0 = sqrtf(1.f + n2);

  U2 w0, w1, w2, w3;
  w0.u = tv.x; w1.u = tv.y; w2.u = tv.z; w3.u = tv.w;
  const float2 ta01 = __half22float2(w0.h);
  const float2 ta23 = __half22float2(w1.h);
  const float2 tb01 = __half22float2(w2.h);
  const float2 tb23 = __half22float2(w3.h);

  float dot = sA0 * ta01.x;
  dot = fmaf(sA1, ta01.y, dot); dot = fmaf(sA2, ta23.x, dot);
  dot = fmaf(sA3, ta23.y, dot);
  dot = fmaf(sB0, tb01.x, dot); dot = fmaf(sB1, tb01.y, dot);
  dot = fmaf(sB2, tb23.x, dot); dot = fmaf(sB3, tb23.y, dot);

  float tsq = ta01.x * ta01.x;
  tsq = fmaf(ta01.y, ta01.y, tsq); tsq = fmaf(ta23.x, ta23.x, tsq);
  tsq = fmaf(ta23.y, ta23.y, tsq);
  tsq = fmaf(tb01.x, tb01.x, tsq); tsq = fmaf(tb01.y, tb01.y, tsq);
  tsq = fmaf(tb23.x, tb23.x, tsq); tsq = fmaf(tb23.y, tb23.y, tsq);

  dot += __shfl_xor(dot, 1);
  dot += __shfl_xor(dot, 2);
  tsq += __shfl_xor(tsq, 1);
  tsq += __shfl_xor(tsq, 2);
  const float t0 = sqrtf(1.f + tsq);          // tail time component

  const float neg_inner = fmaf(ht0, t0, -dot); // -lorentz_inner
  const float ic = fmaxf(neg_inner, 1.0f + 1e-6f);
  const float dist = acoshf(ic);
  if (q == 0 && e < n) out[e] = bsum - dist * dist;
}

// ---------------------------------------------------------------------------
// Fallback (ws too small): fully inline fp32 scalar path (proven).
// ---------------------------------------------------------------------------
__global__ __launch_bounds__(256) void lorentz_fallback_kernel(
    const int* __restrict__ heads, const int* __restrict__ rels,
    const int* __restrict__ tails, const float* __restrict__ emb,
    const float* __restrict__ boost_w, const float* __restrict__ rot_w,
    const float* __restrict__ trans_w, const float* __restrict__ bias,
    float* __restrict__ out, int n) {
  int i = blockIdx.x * blockDim.x + threadIdx.x;
  if (i >= n) return;
  int hd = heads[i], rl = rels[i], tl = tails[i];
  const float* hrow = emb + (size_t)hd * EMB_DIM;
  const float* trow = emb + (size_t)tl * EMB_DIM;
  const float* ro = rot_w   + (size_t)rl * D_;
  const float* tr = trans_w + (size_t)rl * D_;
  float c[HALF_], s[HALF_], kt[D_];
  #pragma unroll
  for (int j = 0; j < HALF_; ++j) { float th = ro[j]; c[j] = cosf(th); s[j] = sinf(th); }
  float s2 = 0.f;
  #pragma unroll
  for (int j = 0; j < D_; ++j) { float v = tr[j]; s2 = fmaf(v, v, s2); }
  float vn = sqrtf(fmaxf(0.01f * s2, 1e-6f));
  float cvn = coshf(vn);
  float k = sinhf(vn) / vn * 0.1f;
  #pragma unroll
  for (int j = 0; j < D_; ++j) kt[j] = k * tr[j];
  float rap = fminf(fmaxf(boost_w[(size_t)rl * D_], -2.f), 2.f);
  float c0 = coshf(rap), s0 = sinhf(rap);
  float x0 = hrow[0];
  float r[D_];
  #pragma unroll
  for (int j = 0; j < HALF_; ++j) {
    float a = hrow[1 + j], b = hrow[1 + HALF_ + j];
    r[j] = c[j] * a - s[j] * b;
    r[HALF_ + j] = s[j] * a + c[j] * b;
  }
  r[0] = fmaf(x0, s0, r[0] * c0);
  float t0 = trow[0], n2 = 0.f, dot = 0.f;
  #pragma unroll
  for (int j = 0; j < D_; ++j) {
    float rsv = fmaf(cvn, r[j], kt[j]);
    n2  = fmaf(rsv, rsv, n2);
    dot = fmaf(rsv, trow[1 + j], dot);
  }
  float ht0 = sqrtf(1.f + n2);
  float neg_inner = fmaf(ht0, t0, -dot);
  float ic = fmaxf(neg_inner, 1.0f + 1e-6f);
  float dist = acoshf(ic);
  out[i] = bias[hd] + bias[tl] - dist * dist;
}

extern "C" void kernel_launch(void* const* d_in, const int* in_sizes, int n_in,
                              void* d_out, int out_size, void* d_ws, size_t ws_size,
                              hipStream_t stream) {
  const int*   heads  = (const int*)d_in[0];
  const int*   rels   = (const int*)d_in[1];
  const int*   tails  = (const int*)d_in[2];
  const float* emb    = (const float*)d_in[3];
  const float* boostw = (const float*)d_in[4];
  const float* rotw   = (const float*)d_in[5];
  const float* transw = (const float*)d_in[6];
  const float* bias   = (const float*)d_in[7];
  float* out = (float*)d_out;
  int n = in_sizes[0];  // B = 1048576

  dim3 block(256);

  if (ws_size >= H16_BYTES + T16_BYTES + HP_BYTES) {
    unsigned int* h16 = (unsigned int*)d_ws;
    unsigned short* tab16 = (unsigned short*)((char*)d_ws + H16_BYTES);
    float4* hp_tab = (float4*)((char*)d_ws + H16_BYTES + T16_BYTES);
    prep_kernel<<<dim3(REPACK_BLOCKS + TAB_BLOCKS), block, 0, stream>>>(
        emb, boostw, rotw, transw, h16, tab16, hp_tab);
    dim3 grid_main((n + 63) / 64);   // 4 lanes per element, 64 elems/block
    lorentz_coop_kernel<<<grid_main, block, 0, stream>>>(
        heads, rels, tails, h16, tab16, hp_tab, bias, out, n);
  } else {
    dim3 grid((n + 255) / 256);
    lorentz_fallback_kernel<<<grid, block, 0, stream>>>(
        heads, rels, tails, emb, boostw, rotw, transw, bias, out, n);
  }
}